// Round 1
// baseline (16.926 us; speedup 1.0000x reference)
//
#include <hip/hip_runtime.h>

#define X_COORD_START 10
#define Y_COORD_START 21
#define EOS_TOKEN     39
#define MAX_REACH     5.0f
#define WINDOW_SIZE   4

// Row geometry: input_ids is (2048, 2048) int32.
// x_tok = cols 2,4,...,2046  (1023 entries), y_tok = cols 3,5,...,2047.
#define ROW_LEN 2048
#define NPAIRS  1023   // H
#define NROWS   2048
#define BLOCK   1024   // 16 waves

__global__ __launch_bounds__(BLOCK)
void reach_row_kernel(const int* __restrict__ ids,
                      float* __restrict__ per_seq,
                      float* __restrict__ valid_f) {
    const int row  = blockIdx.x;
    const int t    = threadIdx.x;
    const int lane = t & 63;
    const int wid  = t >> 6;          // 0..15

    __shared__ float lx[NPAIRS];
    __shared__ float ly[NPAIRS];
    __shared__ int   wave_sums[16];
    __shared__ int   wave_off[17];
    __shared__ float wave_acc[16];

    const int* base = ids + (size_t)row * ROW_LEN;

    int   v  = 0;
    float xc = 0.f, yc = 0.f;
    if (t < NPAIRS) {
        // byte offset of (base + 2 + 2t) is 8-byte aligned -> int2 load
        int2 p = *reinterpret_cast<const int2*>(base + 2 + 2 * t);
        const int x = p.x, y = p.y;
        v  = (x >= X_COORD_START) & (x < Y_COORD_START) &
             (y >= Y_COORD_START) & (y < EOS_TOKEN);
        xc = (float)(x - X_COORD_START);
        yc = (float)(y - Y_COORD_START + 1);
    }

    // ---- stable compaction: exclusive prefix sum of `v` over the block ----
    int incl = v;
    #pragma unroll
    for (int off = 1; off < 64; off <<= 1) {
        int n = __shfl_up(incl, off);
        if (lane >= off) incl += n;
    }
    if (lane == 63) wave_sums[wid] = incl;
    __syncthreads();
    if (t == 0) {
        int s = 0;
        #pragma unroll
        for (int w = 0; w < 16; ++w) { wave_off[w] = s; s += wave_sums[w]; }
        wave_off[16] = s;              // total valid count
    }
    __syncthreads();

    const int excl  = wave_off[wid] + incl - v;
    const int count = wave_off[16];

    if (v) { lx[excl] = xc; ly[excl] = yc; }
    __syncthreads();

    // ---- distance / hinge pass over compacted holds ----
    float acc = 0.f;
    for (int i = WINDOW_SIZE + t; i < count; i += BLOCK) {
        const float xi = lx[i], yi = ly[i];
        float md = 1e30f;
        #pragma unroll
        for (int j = 1; j <= WINDOW_SIZE; ++j) {
            const float dx = xi - lx[i - j];
            const float dy = yi - ly[i - j];
            const float sq = dx * dx + dy * dy;
            const float d  = (sq > 0.f) ? sqrtf(sq) : 0.f;
            md = fminf(md, d);
        }
        acc += fmaxf(md - MAX_REACH, 0.f);
    }

    // ---- block reduction of acc ----
    #pragma unroll
    for (int off = 32; off > 0; off >>= 1) acc += __shfl_down(acc, off);
    if (lane == 0) wave_acc[wid] = acc;
    __syncthreads();
    if (t == 0) {
        float s = 0.f;
        #pragma unroll
        for (int w = 0; w < 16; ++w) s += wave_acc[w];
        const bool  seq_valid = (count >= WINDOW_SIZE + 1);
        const float nchecks   = (float)max(count - WINDOW_SIZE, 1);
        per_seq[row] = seq_valid ? (s / nchecks) : 0.f;
        valid_f[row] = seq_valid ? 1.f : 0.f;
    }
}

__global__ __launch_bounds__(BLOCK)
void reach_finalize_kernel(const float* __restrict__ per_seq,
                           const float* __restrict__ valid_f,
                           float* __restrict__ out) {
    const int t    = threadIdx.x;
    const int lane = t & 63;
    const int wid  = t >> 6;

    __shared__ float ws_s[16];
    __shared__ float ws_n[16];

    float s = per_seq[t] + per_seq[t + BLOCK];
    float n = valid_f[t] + valid_f[t + BLOCK];

    #pragma unroll
    for (int off = 32; off > 0; off >>= 1) {
        s += __shfl_down(s, off);
        n += __shfl_down(n, off);
    }
    if (lane == 0) { ws_s[wid] = s; ws_n[wid] = n; }
    __syncthreads();
    if (t == 0) {
        float st = 0.f, nt = 0.f;
        #pragma unroll
        for (int w = 0; w < 16; ++w) { st += ws_s[w]; nt += ws_n[w]; }
        out[0] = (nt > 0.f) ? (st / nt) : 0.f;   // PENALTY_SCALE = 1.0
    }
}

extern "C" void kernel_launch(void* const* d_in, const int* in_sizes, int n_in,
                              void* d_out, int out_size, void* d_ws, size_t ws_size,
                              hipStream_t stream) {
    const int* ids = (const int*)d_in[0];
    float* out     = (float*)d_out;

    float* per_seq = (float*)d_ws;              // NROWS floats
    float* valid_f = per_seq + NROWS;           // NROWS floats

    reach_row_kernel<<<NROWS, BLOCK, 0, stream>>>(ids, per_seq, valid_f);
    reach_finalize_kernel<<<1, BLOCK, 0, stream>>>(per_seq, valid_f, out);
}